// Round 2
// baseline (702.592 us; speedup 1.0000x reference)
//
#include <hip/hip_runtime.h>

// MultilevelROIAligner: feats [8,{256,128,64,32}^2,256] fp32, boxes [8,256,4],
// out [8,256,7,7,256] fp32.
//
// One 256-thread block (4 waves) per box (b,n). All box/level math is
// wave-uniform; the 49 (p,q) grid points are distributed across the 4 waves
// (k ≡ wave (mod 4)), 2 points in flight per wave for MLP. Each lane loads
// 4 channels (float4) from the 4 bilinear corner rows (coalesced 1 KB/wave
// per corner) and writes 1 float4 non-temporally (output is write-once).
// Keeping all 49 points of a box on one CU gives L1/L2 corner-row reuse
// (each corner row feeds up to 4 neighboring grid points).

typedef float v4f __attribute__((ext_vector_type(4)));

#define NCH  256   // channels
#define NBOX 256   // boxes per batch

__global__ __launch_bounds__(256)
void roi_align_kernel(const float* __restrict__ f2,
                      const float* __restrict__ f3,
                      const float* __restrict__ f4,
                      const float* __restrict__ f5,
                      const float* __restrict__ boxes,
                      float* __restrict__ out)
{
    const int bn = blockIdx.x;           // b*NBOX + n
    const int b  = bn >> 8;              // NBOX == 256

    // ---- box (uniform across block -> scalar) ----
    const float* bx = boxes + (size_t)bn * 4;
    const float by1 = bx[0], bx1v = bx[1], by2 = bx[2], bx2v = bx[3];
    const float bh = by2 - by1;
    const float bw = bx2v - bx1v;

    // level assignment: floor(log2(sqrt(h*w)/224)) + 4, clipped to [2,5]
    const float as = sqrtf(bh * bw);
    float levf = floorf(log2f(as / 224.0f)) + 4.0f;
    levf = fminf(fmaxf(levf, 2.0f), 5.0f);
    const float scale = exp2f(levf);     // exact power of two
    const int   lev0  = (int)levf - 2;

    const float y0b = by1 / scale;
    const float x0b = bx1v / scale;
    const float bhp = bh / scale;        // keep R1's exact op order
    const float bwp = bw / scale;

    const int   W   = 256 >> lev0;       // levels are square: H == W
    const float bnd = (float)(W - 1);

    const float* base;
    if      (lev0 == 0) base = f2 + (size_t)b * (256u * 256u * NCH);
    else if (lev0 == 1) base = f3 + (size_t)b * (128u * 128u * NCH);
    else if (lev0 == 2) base = f4 + (size_t)b * ( 64u *  64u * NCH);
    else                base = f5 + (size_t)b * ( 32u *  32u * NCH);

    const int wv = threadIdx.x >> 6;     // wave id 0..3
    const int t  = threadIdx.x & 63;     // lane -> 4 channels via float4

    float* outbn = out + (size_t)bn * 49 * NCH;

    // per-point corner addresses + bilinear weights (uniform math per wave)
    auto corners = [&](int k,
                       const v4f*& r00, const v4f*& r01,
                       const v4f*& r10, const v4f*& r11,
                       float& w00, float& w01, float& w10, float& w11) {
        const int p = k / 7;
        const int q = k - p * 7;
        const float gy = y0b + ((float)p + 0.5f) * bhp / 7.0f;
        const float gx = x0b + ((float)q + 0.5f) * bwp / 7.0f;
        const float fy0 = fminf(fmaxf(floorf(gy), 0.0f), bnd);
        const float fy1 = fminf(fy0 + 1.0f, bnd);
        const float fx0 = fminf(fmaxf(floorf(gx), 0.0f), bnd);
        const float fx1 = fminf(fx0 + 1.0f, bnd);
        const float ly = gy - fy0, lx = gx - fx0;
        const float ky0 = 1.0f - ly, kx0 = 1.0f - lx;
        const int yi0 = (int)fy0, yi1 = (int)fy1;
        const int xi0 = (int)fx0, xi1 = (int)fx1;
        r00 = (const v4f*)(base + (size_t)(yi0 * W + xi0) * NCH) + t;
        r01 = (const v4f*)(base + (size_t)(yi0 * W + xi1) * NCH) + t;
        r10 = (const v4f*)(base + (size_t)(yi1 * W + xi0) * NCH) + t;
        r11 = (const v4f*)(base + (size_t)(yi1 * W + xi1) * NCH) + t;
        w00 = ky0 * kx0; w01 = ky0 * lx; w10 = ly * kx0; w11 = ly * lx;
    };

    // wave wv covers k ≡ wv (mod 4): iterate k += 8, pairing (k, k+4)
    for (int k = wv; k < 49; k += 8) {
        const v4f *a00, *a01, *a10, *a11, *c00, *c01, *c10, *c11;
        float aw00, aw01, aw10, aw11, cw00, cw01, cw10, cw11;

        corners(k, a00, a01, a10, a11, aw00, aw01, aw10, aw11);
        const bool two = (k + 4) < 49;
        const int  k2  = two ? k + 4 : k;          // dup A when no pair
        corners(k2, c00, c01, c10, c11, cw00, cw01, cw10, cw11);

        // issue all 8 corner loads before any use (MLP)
        const v4f va00 = *a00, va01 = *a01, va10 = *a10, va11 = *a11;
        const v4f vc00 = *c00, vc01 = *c01, vc10 = *c10, vc11 = *c11;

        v4f oa = va00 * aw00 + va01 * aw01 + va10 * aw10 + va11 * aw11;
        __builtin_nontemporal_store(oa, (v4f*)(outbn + (size_t)k * NCH) + t);

        if (two) {
            v4f oc = vc00 * cw00 + vc01 * cw01 + vc10 * cw10 + vc11 * cw11;
            __builtin_nontemporal_store(oc, (v4f*)(outbn + (size_t)k2 * NCH) + t);
        }
    }
}

extern "C" void kernel_launch(void* const* d_in, const int* in_sizes, int n_in,
                              void* d_out, int out_size, void* d_ws, size_t ws_size,
                              hipStream_t stream) {
    const float* f2    = (const float*)d_in[0];
    const float* f3    = (const float*)d_in[1];
    const float* f4    = (const float*)d_in[2];
    const float* f5    = (const float*)d_in[3];
    const float* boxes = (const float*)d_in[4];
    float* out = (float*)d_out;

    const int nblocks = 8 * NBOX;   // one block per box = 2048
    roi_align_kernel<<<nblocks, 256, 0, stream>>>(f2, f3, f4, f5, boxes, out);
}